// Round 2
// baseline (254.644 us; speedup 1.0000x reference)
//
#include <hip/hip_runtime.h>
#include <math.h>

// Static problem shape (from reference setup_inputs)
#define BB    256                // graphs
#define NPER  512                // nodes per graph
#define DD    256                // feature dim
#define KK    256                // kept nodes per graph
#define EPG   (NPER * 16)        // 8192 edges per graph
#define NN    (BB * NPER)
#define EE    (BB * EPG)

// native clang vector type — required by __builtin_nontemporal_store
typedef float vf4 __attribute__((ext_vector_type(4)));

// ---------------- k_fused: GEMV + per-graph pipeline, 1024 threads ----------
// edge loads issued first (latency hidden under BW-bound dot phase) ->
// fused x@W dot (wave per 4 rows, 32 rows/wave) -> degrees -> scale h ->
// LDS agg -> score -> hybrid bitonic top-256 -> feat gather+scale -> edge mask
// One block per graph (grid 256 == CU count), no global syncs, no workspace.
__global__ __launch_bounds__(1024) void k_fused(
        const float* __restrict__ x,
        const float* __restrict__ W,
        const float* __restrict__ b,
        const int* __restrict__ src, const int* __restrict__ dst,
        float* __restrict__ feat, float* __restrict__ out_perm,
        float* __restrict__ emask, float* __restrict__ nnn) {
    __shared__ unsigned int es2[EPG / 2];       // 16 KB packed src id pairs
    __shared__ unsigned int ed2[EPG / 2];       // 16 KB packed dst id pairs
    __shared__ int   degs[NPER];
    __shared__ int   degd[NPER];
    __shared__ float hl[NPER];                  // raw dot, then scaled h
    __shared__ float aggl[NPER];
    __shared__ float scl[NPER];
    __shared__ unsigned long long keys[NPER];   // LDS stages of the sort
    __shared__ float keepf[NPER];               // 1.0 if kept else 0.0
    __shared__ int   sel[KK];                   // rank -> local node id
    __shared__ float tsv[KK];                   // rank -> tanh(score)

    const int g = blockIdx.x;
    const int t = threadIdx.x;                  // 0..1023
    const int wave = t >> 6;
    const int lane = t & 63;
    const int nbase = g << 9;

    // ---- issue all edge loads up front; they complete under the dot phase ----
    const int4* s4 = (const int4*)(src + (size_t)g * EPG);
    const int4* d4 = (const int4*)(dst + (size_t)g * EPG);
    int4 sva = s4[t], dva = d4[t];
    int4 svb = s4[t + 1024], dvb = d4[t + 1024];

    if (t < NPER) { degs[t] = 0; degd[t] = 0; aggl[t] = 0.0f; keepf[t] = 0.0f; }

    // ---- fused GEMV: hl[r] = dot(x[nbase+r], W); wave handles 32 rows ----
    // identical arithmetic/reduction order to the old k_dot (bit-exact)
    {
        const float4 wv = ((const float4*)W)[lane];
        const float4* xb = (const float4*)(x + ((size_t)(nbase + (wave << 5)) << 8));
        #pragma unroll
        for (int it = 0; it < 8; ++it) {
            const float4* p = xb + (it << 8);   // 4 rows = 256 float4 per iter
            float4 a0 = p[lane];
            float4 a1 = p[64 + lane];
            float4 a2 = p[128 + lane];
            float4 a3 = p[192 + lane];
            float d0 = a0.x * wv.x + a0.y * wv.y + a0.z * wv.z + a0.w * wv.w;
            float d1 = a1.x * wv.x + a1.y * wv.y + a1.z * wv.z + a1.w * wv.w;
            float d2 = a2.x * wv.x + a2.y * wv.y + a2.z * wv.z + a2.w * wv.w;
            float d3 = a3.x * wv.x + a3.y * wv.y + a3.z * wv.z + a3.w * wv.w;
            #pragma unroll
            for (int off = 32; off > 0; off >>= 1) {
                d0 += __shfl_down(d0, off, 64);
                d1 += __shfl_down(d1, off, 64);
                d2 += __shfl_down(d2, off, 64);
                d3 += __shfl_down(d3, off, 64);
            }
            if (lane == 0) {
                const int r = (wave << 5) + (it << 2);
                hl[r]     = d0;
                hl[r + 1] = d1;
                hl[r + 2] = d2;
                hl[r + 3] = d3;
            }
        }
    }
    __syncthreads();        // B1: LDS inits + raw hl visible

    // ---- pack edges to LDS + degree histograms (edge regs already resident) ----
    {
        unsigned int a0 = (unsigned int)(sva.x - nbase), a1 = (unsigned int)(sva.y - nbase);
        unsigned int a2 = (unsigned int)(sva.z - nbase), a3 = (unsigned int)(sva.w - nbase);
        es2[t * 2]     = a0 | (a1 << 16);
        es2[t * 2 + 1] = a2 | (a3 << 16);
        atomicAdd(&degs[a0], 1); atomicAdd(&degs[a1], 1);
        atomicAdd(&degs[a2], 1); atomicAdd(&degs[a3], 1);
        unsigned int c0 = (unsigned int)(dva.x - nbase), c1 = (unsigned int)(dva.y - nbase);
        unsigned int c2 = (unsigned int)(dva.z - nbase), c3 = (unsigned int)(dva.w - nbase);
        ed2[t * 2]     = c0 | (c1 << 16);
        ed2[t * 2 + 1] = c2 | (c3 << 16);
        atomicAdd(&degd[c0], 1); atomicAdd(&degd[c1], 1);
        atomicAdd(&degd[c2], 1); atomicAdd(&degd[c3], 1);
    }
    {
        int i = t + 1024;
        unsigned int a0 = (unsigned int)(svb.x - nbase), a1 = (unsigned int)(svb.y - nbase);
        unsigned int a2 = (unsigned int)(svb.z - nbase), a3 = (unsigned int)(svb.w - nbase);
        es2[i * 2]     = a0 | (a1 << 16);
        es2[i * 2 + 1] = a2 | (a3 << 16);
        atomicAdd(&degs[a0], 1); atomicAdd(&degs[a1], 1);
        atomicAdd(&degs[a2], 1); atomicAdd(&degs[a3], 1);
        unsigned int c0 = (unsigned int)(dvb.x - nbase), c1 = (unsigned int)(dvb.y - nbase);
        unsigned int c2 = (unsigned int)(dvb.z - nbase), c3 = (unsigned int)(dvb.w - nbase);
        ed2[i * 2]     = c0 | (c1 << 16);
        ed2[i * 2 + 1] = c2 | (c3 << 16);
        atomicAdd(&degd[c0], 1); atomicAdd(&degd[c1], 1);
        atomicAdd(&degd[c2], 1); atomicAdd(&degd[c3], 1);
    }
    __syncthreads();        // B2: degrees final

    // ---- h = hraw * rsqrt(max(deg_out,1)) ----
    if (t < NPER) hl[t] = hl[t] * rsqrtf(fmaxf((float)degs[t], 1.0f));
    __syncthreads();        // B3: scaled h visible

    // ---- agg[dst] += h[src]  (4 packed pairs per thread) ----
    #pragma unroll
    for (int i = t; i < EPG / 2; i += 1024) {
        unsigned int sp = es2[i], dp = ed2[i];
        atomicAdd(&aggl[dp & 0xFFFFu], hl[sp & 0xFFFFu]);
        atomicAdd(&aggl[dp >> 16],     hl[sp >> 16]);
    }
    __syncthreads();        // B4: agg final

    // ---- score + sort key (monotone float->uint; idx asc on ties) ----
    unsigned long long key = 0;
    if (t < NPER) {
        float sc = aggl[t] * rsqrtf(fmaxf((float)degd[t], 1.0f)) + b[0];
        scl[t] = sc;
        unsigned int u = __float_as_uint(sc);
        u = (u & 0x80000000u) ? ~u : (u | 0x80000000u);
        key = ((unsigned long long)u << 32) |
              (unsigned long long)(0xFFFFFFFFu - (unsigned)t);
    }
    __syncthreads();

    // ---- hybrid bitonic sort, 512 keys, descending, stable ----
    // j < 64  -> wave-local shfl_xor stages (no barriers)
    // j >= 64 -> LDS exchange (6 stages total)
    for (int kk = 2; kk <= NPER; kk <<= 1) {
        for (int j = kk >> 1; j > 0; j >>= 1) {
            if (j >= 64) {
                __syncthreads();                    // WAR: prior reads done
                if (t < NPER) keys[t] = key;
                __syncthreads();
                if (t < NPER) {
                    unsigned long long c = keys[t ^ j];
                    bool lower = ((t & j) == 0);
                    bool up    = ((t & kk) == 0);
                    bool takeMax = (up == lower);
                    key = takeMax ? (key >= c ? key : c)
                                  : (key >= c ? c : key);
                }
            } else {
                if (t < NPER) {
                    unsigned long long c = __shfl_xor(key, j, 64);
                    bool lower = ((t & j) == 0);
                    bool up    = ((t & kk) == 0);
                    bool takeMax = (up == lower);
                    key = takeMax ? (key >= c ? key : c)
                                  : (key >= c ? c : key);
                }
            }
        }
    }

    // ---- top-256: perm, keep flags, sel, tanh(score) ----
    if (t < KK) {
        int idx = (int)(0xFFFFFFFFu - (unsigned int)(key & 0xFFFFFFFFull));
        out_perm[(g << 8) + t] = (float)(nbase + idx);
        sel[t] = idx;
        tsv[t] = tanhf(scl[idx]);
        keepf[idx] = 1.0f;
    }
    __syncthreads();

    // ---- feat = x[sel] * tanh(score)  (wave per row, 16 rows/wave) ----
    // x slab is LLC-resident from the dot phase; non-temporal stores keep it so.
    #pragma unroll
    for (int it = 0; it < 16; it += 2) {
        const int j0 = wave * 16 + it, j1 = j0 + 1;
        const int l0 = sel[j0], l1 = sel[j1];
        const float s0 = tsv[j0], s1 = tsv[j1];
        const float4* q0 = (const float4*)(x + ((size_t)(nbase + l0) << 8));
        const float4* q1 = (const float4*)(x + ((size_t)(nbase + l1) << 8));
        float4 v0 = q0[lane], v1 = q1[lane];
        vf4 o0 = { v0.x * s0, v0.y * s0, v0.z * s0, v0.w * s0 };
        vf4 o1 = { v1.x * s1, v1.y * s1, v1.z * s1, v1.w * s1 };
        vf4* f0 = (vf4*)(feat + ((size_t)((g << 8) + j0) << 8)) + lane;
        vf4* f1 = (vf4*)(feat + ((size_t)((g << 8) + j1) << 8)) + lane;
        __builtin_nontemporal_store(o0, f0);
        __builtin_nontemporal_store(o1, f1);
    }

    // ---- edge mask (packed LDS reads, non-temporal float4 stores) ----
    vf4* em4 = (vf4*)(emask + ((size_t)g << 13));
    #pragma unroll
    for (int i = t; i < EPG / 4; i += 1024) {
        unsigned int sp0 = es2[i * 2], sp1 = es2[i * 2 + 1];
        unsigned int dp0 = ed2[i * 2], dp1 = ed2[i * 2 + 1];
        vf4 m;
        m.x = keepf[sp0 & 0xFFFFu] * keepf[dp0 & 0xFFFFu];
        m.y = keepf[sp0 >> 16]     * keepf[dp0 >> 16];
        m.z = keepf[sp1 & 0xFFFFu] * keepf[dp1 & 0xFFFFu];
        m.w = keepf[sp1 >> 16]     * keepf[dp1 >> 16];
        __builtin_nontemporal_store(m, &em4[i]);
    }
    if (g == 0 && t < BB) nnn[t] = (float)KK;
}

extern "C" void kernel_launch(void* const* d_in, const int* in_sizes, int n_in,
                              void* d_out, int out_size, void* d_ws, size_t ws_size,
                              hipStream_t stream) {
    const float* x   = (const float*)d_in[0];
    const float* W   = (const float*)d_in[1];
    const float* b   = (const float*)d_in[2];
    const int*   src = (const int*)d_in[3];
    const int*   dst = (const int*)d_in[4];
    // d_in[5] = num_nodes (uniform 512, unused)

    float* out   = (float*)d_out;
    float* feat  = out;                                   // [B*k, D]
    float* operm = feat + (size_t)BB * KK * DD;           // [B*k]
    float* emask = operm + (size_t)BB * KK;               // [E]
    float* nnn   = emask + (size_t)EE;                    // [B]

    // single fused kernel: no workspace, no inter-kernel drain
    k_fused<<<BB, 1024, 0, stream>>>(x, W, b, src, dst,
                                     feat, operm, emask, nnn);
}

// Round 3
// 254.595 us; speedup vs baseline: 1.0002x; 1.0002x over previous
//
#include <hip/hip_runtime.h>
#include <math.h>

// Static problem shape (from reference setup_inputs)
#define BB    256                // graphs
#define NPER  512                // nodes per graph
#define DD    256                // feature dim
#define KK    256                // kept nodes per graph
#define EPG   (NPER * 16)        // 8192 edges per graph
#define NN    (BB * NPER)
#define EE    (BB * EPG)

// native clang vector type — required by __builtin_nontemporal_store
typedef float vf4 __attribute__((ext_vector_type(4)));

// ---------------- k_fused: wave-specialized per-graph pipeline --------------
// waves 0-7:  GEMV hl[r] = dot(x[r], W)            (memory-BW bound)
// waves 8-15: edge load/pack + degree histograms    (hidden under GEMV)
// then: scale h -> LDS agg -> score -> bitonic top-256 -> feat gather + mask
// One block per graph (grid 256 == CU count). launch_bounds(1024,4) -> 128 VGPR
// budget (grid==CUs so a 2nd block never co-resides; extra regs are free MLP).
__global__ __launch_bounds__(1024, 4) void k_fused(
        const float* __restrict__ x,
        const float* __restrict__ W,
        const float* __restrict__ b,
        const int* __restrict__ src, const int* __restrict__ dst,
        float* __restrict__ feat, float* __restrict__ out_perm,
        float* __restrict__ emask, float* __restrict__ nnn) {
    __shared__ unsigned int es2[EPG / 2];       // 16 KB packed src id pairs
    __shared__ unsigned int ed2[EPG / 2];       // 16 KB packed dst id pairs
    __shared__ int   degs[NPER];
    __shared__ int   degd[NPER];
    __shared__ float hl[NPER];                  // raw dot, then scaled h
    __shared__ float aggl[NPER];
    __shared__ float scl[NPER];
    __shared__ unsigned long long keys[NPER];   // LDS stages of the sort
    __shared__ float keepf[NPER];               // 1.0 if kept else 0.0
    __shared__ int   sel[KK];                   // rank -> local node id
    __shared__ float tsv[KK];                   // rank -> tanh(score)

    const int g = blockIdx.x;
    const int t = threadIdx.x;                  // 0..1023
    const int wave = t >> 6;
    const int lane = t & 63;
    const int nbase = g << 9;

    // ---- LDS init by edge waves (GEMV waves reach B0 immediately) ----
    if (t >= 512) {
        const int tt = t - 512;
        degs[tt] = 0; degd[tt] = 0; aggl[tt] = 0.0f; keepf[tt] = 0.0f;
    }
    __syncthreads();        // B0: histograms may start

    if (wave < 8) {
        // ---- GEMV: wave handles 64 rows, 16 iters x 4 rows ----
        // same shfl reduction order as the verified kernel (bit-exact)
        const float4 wv = ((const float4*)W)[lane];
        const float4* xb = (const float4*)(x + ((size_t)(nbase + (wave << 6)) << 8));
        #pragma unroll 4
        for (int it = 0; it < 16; ++it) {
            const float4* p = xb + (it << 8);   // 4 rows = 256 float4 per iter
            float4 a0 = p[lane];
            float4 a1 = p[64 + lane];
            float4 a2 = p[128 + lane];
            float4 a3 = p[192 + lane];
            float d0 = a0.x * wv.x + a0.y * wv.y + a0.z * wv.z + a0.w * wv.w;
            float d1 = a1.x * wv.x + a1.y * wv.y + a1.z * wv.z + a1.w * wv.w;
            float d2 = a2.x * wv.x + a2.y * wv.y + a2.z * wv.z + a2.w * wv.w;
            float d3 = a3.x * wv.x + a3.y * wv.y + a3.z * wv.z + a3.w * wv.w;
            #pragma unroll
            for (int off = 32; off > 0; off >>= 1) {
                d0 += __shfl_down(d0, off, 64);
                d1 += __shfl_down(d1, off, 64);
                d2 += __shfl_down(d2, off, 64);
                d3 += __shfl_down(d3, off, 64);
            }
            if (lane == 0) {
                const int r = (wave << 6) + (it << 2);
                hl[r]     = d0;
                hl[r + 1] = d1;
                hl[r + 2] = d2;
                hl[r + 3] = d3;
            }
        }
    } else {
        // ---- edges: 512 threads x 4 int4 (src) + 4 int4 (dst) ----
        const int tt = t - 512;
        const int4* s4 = (const int4*)(src + (size_t)g * EPG);
        const int4* d4 = (const int4*)(dst + (size_t)g * EPG);
        #pragma unroll
        for (int c = 0; c < 4; ++c) {
            const int i = tt + (c << 9);        // int4 index 0..2047
            int4 sv = s4[i], dv = d4[i];
            unsigned int a0 = (unsigned int)(sv.x - nbase), a1 = (unsigned int)(sv.y - nbase);
            unsigned int a2 = (unsigned int)(sv.z - nbase), a3 = (unsigned int)(sv.w - nbase);
            es2[i * 2]     = a0 | (a1 << 16);
            es2[i * 2 + 1] = a2 | (a3 << 16);
            atomicAdd(&degs[a0], 1); atomicAdd(&degs[a1], 1);
            atomicAdd(&degs[a2], 1); atomicAdd(&degs[a3], 1);
            unsigned int c0 = (unsigned int)(dv.x - nbase), c1 = (unsigned int)(dv.y - nbase);
            unsigned int c2 = (unsigned int)(dv.z - nbase), c3 = (unsigned int)(dv.w - nbase);
            ed2[i * 2]     = c0 | (c1 << 16);
            ed2[i * 2 + 1] = c2 | (c3 << 16);
            atomicAdd(&degd[c0], 1); atomicAdd(&degd[c1], 1);
            atomicAdd(&degd[c2], 1); atomicAdd(&degd[c3], 1);
        }
    }
    __syncthreads();        // B1: hl raw + edges + degrees final

    // ---- h = hraw * rsqrt(max(deg_out,1)) ----
    if (t < NPER) hl[t] = hl[t] * rsqrtf(fmaxf((float)degs[t], 1.0f));
    __syncthreads();        // B2: scaled h visible

    // ---- agg[dst] += h[src]  (4 packed pairs per thread) ----
    #pragma unroll
    for (int i = t; i < EPG / 2; i += 1024) {
        unsigned int sp = es2[i], dp = ed2[i];
        atomicAdd(&aggl[dp & 0xFFFFu], hl[sp & 0xFFFFu]);
        atomicAdd(&aggl[dp >> 16],     hl[sp >> 16]);
    }
    __syncthreads();        // B3: agg final

    // ---- score + sort key (monotone float->uint; idx asc on ties) ----
    unsigned long long key = 0;
    if (t < NPER) {
        float sc = aggl[t] * rsqrtf(fmaxf((float)degd[t], 1.0f)) + b[0];
        scl[t] = sc;
        unsigned int u = __float_as_uint(sc);
        u = (u & 0x80000000u) ? ~u : (u | 0x80000000u);
        key = ((unsigned long long)u << 32) |
              (unsigned long long)(0xFFFFFFFFu - (unsigned)t);
    }

    // ---- hybrid bitonic sort, 512 keys, descending, stable ----
    // j < 64  -> wave-local shfl_xor stages (no barriers)
    // j >= 64 -> LDS exchange (6 stages total)
    for (int kk = 2; kk <= NPER; kk <<= 1) {
        for (int j = kk >> 1; j > 0; j >>= 1) {
            if (j >= 64) {
                __syncthreads();                    // WAR: prior reads done
                if (t < NPER) keys[t] = key;
                __syncthreads();
                if (t < NPER) {
                    unsigned long long c = keys[t ^ j];
                    bool lower = ((t & j) == 0);
                    bool up    = ((t & kk) == 0);
                    bool takeMax = (up == lower);
                    key = takeMax ? (key >= c ? key : c)
                                  : (key >= c ? c : key);
                }
            } else {
                if (t < NPER) {
                    unsigned long long c = __shfl_xor(key, j, 64);
                    bool lower = ((t & j) == 0);
                    bool up    = ((t & kk) == 0);
                    bool takeMax = (up == lower);
                    key = takeMax ? (key >= c ? key : c)
                                  : (key >= c ? c : key);
                }
            }
        }
    }

    // ---- top-256: perm, keep flags, sel, tanh(score) ----
    if (t < KK) {
        int idx = (int)(0xFFFFFFFFu - (unsigned int)(key & 0xFFFFFFFFull));
        out_perm[(g << 8) + t] = (float)(nbase + idx);
        sel[t] = idx;
        tsv[t] = tanhf(scl[idx]);
        keepf[idx] = 1.0f;
    }
    __syncthreads();        // B5: sel/tsv/keepf ready

    // ---- edge mask first on waves 8-15 (overlaps feat gather below) ----
    if (wave >= 8) {
        const int tt = t - 512;
        vf4* em4 = (vf4*)(emask + ((size_t)g << 13));
        #pragma unroll
        for (int c = 0; c < 4; ++c) {
            const int i = tt + (c << 9);        // 0..2047
            unsigned int sp0 = es2[i * 2], sp1 = es2[i * 2 + 1];
            unsigned int dp0 = ed2[i * 2], dp1 = ed2[i * 2 + 1];
            vf4 m;
            m.x = keepf[sp0 & 0xFFFFu] * keepf[dp0 & 0xFFFFu];
            m.y = keepf[sp0 >> 16]     * keepf[dp0 >> 16];
            m.z = keepf[sp1 & 0xFFFFu] * keepf[dp1 & 0xFFFFu];
            m.w = keepf[sp1 >> 16]     * keepf[dp1 >> 16];
            __builtin_nontemporal_store(m, &em4[i]);
        }
    }

    // ---- feat = x[sel] * tanh(score): all 16 waves, 16 rows each,
    //      2 chunks of 8 rows with all 8 loads issued before any store ----
    {
        const int base = wave << 4;
        #pragma unroll
        for (int ch = 0; ch < 2; ++ch) {
            const int j0 = base + (ch << 3);
            int   l[8]; float s[8]; float4 v[8];
            #pragma unroll
            for (int u = 0; u < 8; ++u) { l[u] = sel[j0 + u]; s[u] = tsv[j0 + u]; }
            #pragma unroll
            for (int u = 0; u < 8; ++u) {
                v[u] = ((const float4*)(x + ((size_t)(nbase + l[u]) << 8)))[lane];
            }
            #pragma unroll
            for (int u = 0; u < 8; ++u) {
                vf4 o = { v[u].x * s[u], v[u].y * s[u], v[u].z * s[u], v[u].w * s[u] };
                __builtin_nontemporal_store(
                    o, (vf4*)(feat + ((size_t)((g << 8) + j0 + u) << 8)) + lane);
            }
        }
    }
    if (g == 0 && t < BB) nnn[t] = (float)KK;
}

extern "C" void kernel_launch(void* const* d_in, const int* in_sizes, int n_in,
                              void* d_out, int out_size, void* d_ws, size_t ws_size,
                              hipStream_t stream) {
    const float* x   = (const float*)d_in[0];
    const float* W   = (const float*)d_in[1];
    const float* b   = (const float*)d_in[2];
    const int*   src = (const int*)d_in[3];
    const int*   dst = (const int*)d_in[4];
    // d_in[5] = num_nodes (uniform 512, unused)

    float* out   = (float*)d_out;
    float* feat  = out;                                   // [B*k, D]
    float* operm = feat + (size_t)BB * KK * DD;           // [B*k]
    float* emask = operm + (size_t)BB * KK;               // [E]
    float* nnn   = emask + (size_t)EE;                    // [B]

    // single fused kernel: no workspace, no inter-kernel drain
    k_fused<<<BB, 1024, 0, stream>>>(x, W, b, src, dst,
                                     feat, operm, emask, nnn);
}